// Round 1
// baseline (114.457 us; speedup 1.0000x reference)
//
#include <hip/hip_runtime.h>
#include <math.h>

// Problem constants (match reference)
constexpr int B_ = 32;
constexpr int C_ = 32;
constexpr int RES_ = 16;
constexpr int G_ = RES_ * RES_ * RES_;   // 4096
constexpr int N_ = 16384;
constexpr int H_ = 64;
// sqrt(3)/RES
__device__ constexpr float REG_THR = 0.10825317547305483f;

// float -> bf16 bits, round-to-nearest-even (values are finite here).
__device__ __forceinline__ unsigned short f2bf(float f) {
    union { float f; unsigned int u; } v; v.f = f;
    const unsigned int r = v.u + 0x7FFFu + ((v.u >> 16) & 1u);
    return (unsigned short)(r >> 16);
}

// ---------------------------------------------------------------------------
// Kernel 1: per-batch inclusive scan of counts (4096 cells) -> cum[b][G].
// ---------------------------------------------------------------------------
__global__ __launch_bounds__(256) void scan_kernel(const int* __restrict__ counts,
                                                   int* __restrict__ cum) {
    const int b = blockIdx.x;
    const int* cb = counts + b * G_;
    int* ob = cum + b * G_;

    __shared__ int partials[256];
    const int t = threadIdx.x;
    const int base = t * 16;

    int local[16];
    int s = 0;
#pragma unroll
    for (int i = 0; i < 16; ++i) {
        s += cb[base + i];
        local[i] = s;
    }
    partials[t] = s;
    __syncthreads();

    for (int off = 1; off < 256; off <<= 1) {
        int v = (t >= off) ? partials[t - off] : 0;
        __syncthreads();
        partials[t] += v;
        __syncthreads();
    }
    const int prev = (t > 0) ? partials[t - 1] : 0;

#pragma unroll
    for (int i = 0; i < 16; ++i) ob[base + i] = prev + local[i];
}

// ---------------------------------------------------------------------------
// Kernel 2 (Stage A): hx_bf[b, cell, h] = bf16( b1[h] + sum_c W1[h,c]*x[..] )
//
// Best-measured configuration (R8, 110.1 us total). Design decisions, each
// counter-verified in earlier rounds:
//  - LDS copy-out, linear coalesced stores: fixes 5.8x HBM write-amp (R3).
//  - readfirstlane wave-uniform h-offset: weights never become per-lane
//    VMEM loads (R4: divergent weight addrs cost 43 us).
//  - W1/b1 staged in LDS, wave-uniform broadcast reads: removes the s_load
//    lgkmcnt serialization (R5/R7: ~25 us at VALUBusy 21% regardless of
//    wave depth).
//  - bf16 hx storage (RNE): halves the round-trip; out err ~2e-4 << 1.5e-2.
//  - 64 cells/block, PAD=65: all LDS b32 phases conflict-free; 26 KB LDS.
// ---------------------------------------------------------------------------
constexpr int TCELL = 64;     // cells per block
constexpr int PAD = H_ + 1;   // 65
constexpr int WROW = 36;      // W1 LDS row stride (floats)

__global__ __launch_bounds__(256) void hx_kernel(const float* __restrict__ x,
                                                 const float* __restrict__ W1,
                                                 const float* __restrict__ b1,
                                                 unsigned short* __restrict__ hxb) {
    const int b = blockIdx.y;
    const int tile = blockIdx.x * TCELL;
    const int t = threadIdx.x;
    const int cell_l = t & 63;                 // lane = cell
    const int hh = __builtin_amdgcn_readfirstlane((t >> 6) * 16);

    __shared__ float __align__(16) s_w1[H_ * WROW];
    __shared__ float s_hx[TCELL * PAD];

    // Cooperative W1 fill (2176 floats) + b1 into the row pad.
    for (int i = t; i < H_ * 34; i += 256) {
        const int r = i / 34;
        const int c = i - r * 34;
        s_w1[r * WROW + c] = W1[i];
    }
    if (t < H_) s_w1[t * WROW + 34] = b1[t];

    // Coalesced x loads (issue before the barrier to overlap HBM latency).
    const float* xb = x + ((size_t)b * C_) * G_ + tile + cell_l;
    float xv[C_];
#pragma unroll
    for (int c = 0; c < C_; ++c) xv[c] = xb[(size_t)c * G_];
    __syncthreads();

    // 16 h per thread; weight rows from LDS at wave-uniform addresses.
    float* row = s_hx + cell_l * PAD + hh;
#pragma unroll 4
    for (int j = 0; j < 16; ++j) {
        const float* w = s_w1 + (hh + j) * WROW;
        float acc = w[34];                     // b1[h]
#pragma unroll
        for (int c = 0; c < C_; ++c) acc = fmaf(w[c], xv[c], acc);
        row[j] = acc;   // bank = (cell + h)%32 across lanes: conflict-free
    }
    __syncthreads();

    // Copy-out: convert to bf16, pack, linear coalesced uint4 stores.
    unsigned short* ob = hxb + ((size_t)b * G_ + tile) * H_;
#pragma unroll
    for (int k = 0; k < 2; ++k) {
        const int L = (t + k * 256) * 8;       // linear element index
        const int cell = L >> 6;
        const int h = L & 63;
        const float* s = s_hx + cell * PAD + h;
        unsigned int us[4];
#pragma unroll
        for (int q = 0; q < 4; ++q) {
            const unsigned int lo = f2bf(s[2 * q]);
            const unsigned int hi = f2bf(s[2 * q + 1]);
            us[q] = lo | (hi << 16);
        }
        *(uint4*)(ob + L) = make_uint4(us[0], us[1], us[2], us[3]);
    }
}

// ---------------------------------------------------------------------------
// Kernel 3 (Stage B): one thread per (b, n) point.
//   idx = searchsorted(cum[b], n, 'right')  (binary search, LDS copy)
//   h   = relu(bf16->f32(hx[b,idx,:]) + W1[:,32]*r0 + W1[:,33]*r1)
//   out = W2 @ h + b2;  out += exact grid offset;  reg = clip(|out|-thr, 0)
//
// R9 change: the h-loop previously read W1[h*34+32/33] and W2[o*64+h]
// straight from global at uniform addresses — 320 loop-invariant s_loads
// per thread that can't all be hoisted (SGPR budget), i.e. the same
// lgkmcnt-serialization pathology R5/R7 measured in hx_kernel. Stage the
// 5 per-h coefficients in LDS (s_cf[h][8]: w32, w33, w2_0, w2_1, w2_2)
// and read them with wave-uniform broadcast ds_read_b128 + ds_read_b32.
// +2 KB LDS (18 KB total -> still 8 blocks/CU, full 32-wave occupancy).
// ---------------------------------------------------------------------------
constexpr int CFS = 8;   // s_cf row stride (floats, 32 B: b128-aligned)

__global__ __launch_bounds__(256) void point_kernel(
    const unsigned short* __restrict__ hxb, const float* __restrict__ b_rnd,
    const float* __restrict__ W1, const float* __restrict__ W2,
    const float* __restrict__ b2, const int* __restrict__ cum,
    float* __restrict__ out0, float* __restrict__ reg_out) {
    const int b = blockIdx.y;
    const int n = blockIdx.x * 256 + threadIdx.x;
    const int t = threadIdx.x;

    __shared__ int s_cum[G_];
    __shared__ float __align__(16) s_cf[H_ * CFS];

    // Per-h coefficient table: [w32, w33, W2_0, W2_1, W2_2, pad, pad, pad].
    if (t < H_) {
        s_cf[t * CFS + 0] = W1[t * 34 + 32];
        s_cf[t * CFS + 1] = W1[t * 34 + 33];
        s_cf[t * CFS + 2] = W2[0 * H_ + t];
        s_cf[t * CFS + 3] = W2[1 * H_ + t];
        s_cf[t * CFS + 4] = W2[2 * H_ + t];
    }
    const int* cb = cum + b * G_;
#pragma unroll
    for (int i = 0; i < G_ / 256; ++i) s_cum[t + i * 256] = cb[t + i * 256];
    __syncthreads();

    int lo = 0, hi = G_ - 1;
#pragma unroll
    for (int it = 0; it < 12; ++it) {
        const int mid = (lo + hi) >> 1;
        if (s_cum[mid] > n) hi = mid; else lo = mid + 1;
        if (lo >= hi) hi = lo;
    }
    const int idx = lo;

    const float r0 = b_rnd[((size_t)b * 2 + 0) * N_ + n];
    const float r1 = b_rnd[((size_t)b * 2 + 1) * N_ + n];
    const unsigned short* hp = hxb + ((size_t)b * G_ + idx) * H_;

    float o0 = b2[0], o1 = b2[1], o2 = b2[2];
#pragma unroll
    for (int g = 0; g < 8; ++g) {              // 8 h per group, one uint4
        const uint4 u = *(const uint4*)(hp + g * 8);
        const unsigned int uw[4] = {u.x, u.y, u.z, u.w};
        float hvv[8];
#pragma unroll
        for (int q = 0; q < 4; ++q) {
            union { unsigned int u; float f; } a, bwd;
            a.u = uw[q] << 16;                 // even h
            bwd.u = uw[q] & 0xFFFF0000u;       // odd h
            hvv[2 * q] = a.f;
            hvv[2 * q + 1] = bwd.f;
        }
#pragma unroll
        for (int j = 0; j < 8; ++j) {
            const int h = g * 8 + j;
            // Wave-uniform broadcast LDS reads (no bank conflicts):
            const float4 cf = *(const float4*)(s_cf + h * CFS);   // w32,w33,w20,w21
            const float w22 = s_cf[h * CFS + 4];
            float hv = hvv[j];
            hv = fmaf(cf.x, r0, hv);
            hv = fmaf(cf.y, r1, hv);
            hv = fmaxf(hv, 0.0f);
            o0 = fmaf(cf.z, hv, o0);
            o1 = fmaf(cf.w, hv, o1);
            o2 = fmaf(w22, hv, o2);
        }
    }

    const float nrm = sqrtf(o0 * o0 + o1 * o1 + o2 * o2);
    const float reg = fmaxf(nrm - REG_THR, 0.0f);

    // grid_o[k][idx] = (i_k + 0.5)/16 - 0.5, exact in fp32 from idx bits.
    o0 += (float)((idx >> 8) & 15) * 0.0625f - 0.46875f;
    o1 += (float)((idx >> 4) & 15) * 0.0625f - 0.46875f;
    o2 += (float)(idx & 15) * 0.0625f - 0.46875f;

    float* p = out0 + ((size_t)b * 3) * N_ + n;
    p[0]              = o0;
    p[N_]             = o1;
    p[2 * (size_t)N_] = o2;
    reg_out[(size_t)b * N_ + n] = reg;
}

// ---------------------------------------------------------------------------
extern "C" void kernel_launch(void* const* d_in, const int* in_sizes, int n_in,
                              void* d_out, int out_size, void* d_ws, size_t ws_size,
                              hipStream_t stream) {
    const float* x      = (const float*)d_in[0];  // (B, C, RES, RES, RES)
    const int*   counts = (const int*)  d_in[1];  // (B, G)
    const float* b_rnd  = (const float*)d_in[2];  // (B, 2, N)
    // d_in[3] = grid_o: unused (recomputed exactly from idx bits)
    const float* W1     = (const float*)d_in[4];  // (H, C+2)
    const float* b1     = (const float*)d_in[5];  // (H,)
    const float* W2     = (const float*)d_in[6];  // (3, H)
    const float* b2     = (const float*)d_in[7];  // (3,)

    float* out  = (float*)d_out;                  // (B, 3, N) then (B, N)
    float* rout = out + (size_t)B_ * 3 * N_;

    int* cum = (int*)d_ws;                        // B*G ints = 512 KB
    unsigned short* hxb =
        (unsigned short*)((char*)d_ws + (size_t)B_ * G_ * sizeof(int));
                                                  // B*G*H bf16 = 16.8 MB

    scan_kernel<<<B_, 256, 0, stream>>>(counts, cum);

    dim3 gridA(G_ / TCELL, B_);
    hx_kernel<<<gridA, 256, 0, stream>>>(x, W1, b1, hxb);

    dim3 gridB(N_ / 256, B_);
    point_kernel<<<gridB, 256, 0, stream>>>(hxb, b_rnd, W1, W2, b2,
                                            cum, out, rout);
}

// Round 2
// 109.897 us; speedup vs baseline: 1.0415x; 1.0415x over previous
//
#include <hip/hip_runtime.h>
#include <math.h>

// Problem constants (match reference)
constexpr int B_ = 32;
constexpr int C_ = 32;
constexpr int RES_ = 16;
constexpr int G_ = RES_ * RES_ * RES_;   // 4096
constexpr int N_ = 16384;
constexpr int H_ = 64;
// sqrt(3)/RES
__device__ constexpr float REG_THR = 0.10825317547305483f;

// float -> bf16 bits, round-to-nearest-even (values are finite here).
__device__ __forceinline__ unsigned short f2bf(float f) {
    union { float f; unsigned int u; } v; v.f = f;
    const unsigned int r = v.u + 0x7FFFu + ((v.u >> 16) & 1u);
    return (unsigned short)(r >> 16);
}

// ---------------------------------------------------------------------------
// Kernel A (fused): hx compute + per-batch scan/scatter.
//
// hx branch (blockIdx.x < G/TCELL):
//   hx_bf[b, cell, h] = bf16( b1[h] + sum_c W1[h,c]*x[..] )
//   R10 change: TCELL 64 -> 128, TWO cells per thread. The inner loop's
//   weight reads are wave-uniform LDS *broadcasts* on the shared per-CU LDS
//   pipe (~4600 b128-instr/CU at 4-12 cyc = the probable 8-23 us cost that
//   R5/R7 saw as "VALUBusy 21%"). Doubling cells/thread halves the LDS
//   instruction count at unchanged FMA total. LDS 42.5 KB -> 3 blocks/CU.
//
// scan branch (blockIdx.x == G/TCELL, one block per batch):
//   block-scan of counts, then scatter idx[b][n] = cell for the slot range
//   each cell owns. Replaces point-side binary search + 16 KB/block cum
//   staging (R10: removes 33.5 MB L2 re-reads + all point LDS). Writes are
//   ordered/contiguous across threads -> coalesced.
// ---------------------------------------------------------------------------
constexpr int TCELL = 128;    // cells per block (2 per thread)
constexpr int PAD = H_ + 1;   // 65
constexpr int WROW = 36;      // W1 LDS row stride (floats; 144B = b128-aligned)

__global__ __launch_bounds__(256) void hx_scan_kernel(
    const float* __restrict__ x, const float* __restrict__ W1,
    const float* __restrict__ b1, const int* __restrict__ counts,
    unsigned short* __restrict__ hxb, int* __restrict__ idxarr) {
    const int b = blockIdx.y;
    const int t = threadIdx.x;

    __shared__ float __align__(16) s_w1[H_ * WROW];   // 9.2 KB
    __shared__ float s_hx[TCELL * PAD];               // 33.3 KB

    if (blockIdx.x == G_ / TCELL) {
        // ---- scan + scatter (one block per batch) ----
        int* partials = (int*)s_w1;                   // 1 KB alias
        const int* cb = counts + b * G_;
        const int base = t * 16;
        int local[16];
        int s = 0;
#pragma unroll
        for (int i = 0; i < 16; ++i) { s += cb[base + i]; local[i] = s; }
        partials[t] = s;
        __syncthreads();
        for (int off = 1; off < 256; off <<= 1) {
            int v = (t >= off) ? partials[t - off] : 0;
            __syncthreads();
            partials[t] += v;
            __syncthreads();
        }
        const int prev = (t > 0) ? partials[t - 1] : 0;

        int* ib = idxarr + b * N_;
        int startk = prev;
#pragma unroll
        for (int i = 0; i < 16; ++i) {
            const int endk = prev + local[i];
            const int cell = base + i;
            for (int k = startk; k < endk; ++k) ib[k] = cell;
            startk = endk;
        }
        return;
    }

    // ---- hx branch ----
    const int tile = blockIdx.x * TCELL;
    const int cell_l = t & 63;                 // lane = cell (within half-tile)
    const int hh = __builtin_amdgcn_readfirstlane((t >> 6) * 16);

    // Cooperative W1 fill (2176 floats) + b1 into the row pad.
    for (int i = t; i < H_ * 34; i += 256) {
        const int r = i / 34;
        const int c = i - r * 34;
        s_w1[r * WROW + c] = W1[i];
    }
    if (t < H_) s_w1[t * WROW + 34] = b1[t];

    // Coalesced x loads for BOTH cells (issued before barrier: overlap HBM).
    const float* xb = x + ((size_t)b * C_) * G_ + tile + cell_l;
    float xv0[C_], xv1[C_];
#pragma unroll
    for (int c = 0; c < C_; ++c) {
        xv0[c] = xb[(size_t)c * G_];
        xv1[c] = xb[(size_t)c * G_ + 64];
    }
    __syncthreads();

    // 16 h per thread x 2 cells; one weight-row broadcast feeds 64 FMAs.
    float* row0 = s_hx + cell_l * PAD + hh;
    float* row1 = s_hx + (cell_l + 64) * PAD + hh;
#pragma unroll 4
    for (int j = 0; j < 16; ++j) {
        const float* w = s_w1 + (hh + j) * WROW;
        float a0 = w[34];                      // b1[h]
        float a1 = a0;
#pragma unroll
        for (int c = 0; c < C_; ++c) {
            a0 = fmaf(w[c], xv0[c], a0);
            a1 = fmaf(w[c], xv1[c], a1);
        }
        row0[j] = a0;   // bank = (cell + h)%32 across lanes: conflict-free
        row1[j] = a1;
    }
    __syncthreads();

    // Copy-out: convert to bf16, pack, linear coalesced uint4 stores.
    unsigned short* ob = hxb + ((size_t)b * G_ + tile) * H_;
#pragma unroll
    for (int k = 0; k < 4; ++k) {
        const int L = (t + k * 256) * 8;       // linear element index
        const int cell = L >> 6;
        const int h = L & 63;
        const float* s = s_hx + cell * PAD + h;
        unsigned int us[4];
#pragma unroll
        for (int q = 0; q < 4; ++q) {
            const unsigned int lo = f2bf(s[2 * q]);
            const unsigned int hi = f2bf(s[2 * q + 1]);
            us[q] = lo | (hi << 16);
        }
        *(uint4*)(ob + L) = make_uint4(us[0], us[1], us[2], us[3]);
    }
}

// ---------------------------------------------------------------------------
// Kernel B: one thread per (b, n) point.
//   idx = idxarr[b][n]   (precomputed scatter; no LDS, no binary search)
//   h   = relu(bf16->f32(hx[b,idx,:]) + W1[:,32]*r0 + W1[:,33]*r1)
//   out = W2 @ h + b2;  out += exact grid offset;  reg = clip(|out|-thr, 0)
//
// R10: R9's LDS coefficient table REVERTED (it moved wave-uniform reads from
// the free scalar pipe onto the shared LDS pipe; measured +5 us). W1/W2/b2
// reads stay as uniform-address global loads -> s_load + K$, zero VALU/LDS
// cost.
// ---------------------------------------------------------------------------
__global__ __launch_bounds__(256) void point_kernel(
    const unsigned short* __restrict__ hxb, const float* __restrict__ b_rnd,
    const float* __restrict__ W1, const float* __restrict__ W2,
    const float* __restrict__ b2, const int* __restrict__ idxarr,
    float* __restrict__ out0, float* __restrict__ reg_out) {
    const int b = blockIdx.y;
    const int n = blockIdx.x * 256 + threadIdx.x;

    const int idx = idxarr[(size_t)b * N_ + n];
    const float r0 = b_rnd[((size_t)b * 2 + 0) * N_ + n];
    const float r1 = b_rnd[((size_t)b * 2 + 1) * N_ + n];
    const unsigned short* hp = hxb + ((size_t)b * G_ + idx) * H_;

    float o0 = b2[0], o1 = b2[1], o2 = b2[2];
#pragma unroll
    for (int g = 0; g < 8; ++g) {              // 8 h per group, one uint4
        const uint4 u = *(const uint4*)(hp + g * 8);
        const unsigned int uw[4] = {u.x, u.y, u.z, u.w};
        float hvv[8];
#pragma unroll
        for (int q = 0; q < 4; ++q) {
            union { unsigned int u; float f; } a, bwd;
            a.u = uw[q] << 16;                 // even h
            bwd.u = uw[q] & 0xFFFF0000u;       // odd h
            hvv[2 * q] = a.f;
            hvv[2 * q + 1] = bwd.f;
        }
#pragma unroll
        for (int j = 0; j < 8; ++j) {
            const int h = g * 8 + j;
            float hv = hvv[j];
            hv = fmaf(W1[h * 34 + 32], r0, hv);
            hv = fmaf(W1[h * 34 + 33], r1, hv);
            hv = fmaxf(hv, 0.0f);
            o0 = fmaf(W2[0 * H_ + h], hv, o0);
            o1 = fmaf(W2[1 * H_ + h], hv, o1);
            o2 = fmaf(W2[2 * H_ + h], hv, o2);
        }
    }

    const float nrm = sqrtf(o0 * o0 + o1 * o1 + o2 * o2);
    const float reg = fmaxf(nrm - REG_THR, 0.0f);

    // grid_o[k][idx] = (i_k + 0.5)/16 - 0.5, exact in fp32 from idx bits.
    o0 += (float)((idx >> 8) & 15) * 0.0625f - 0.46875f;
    o1 += (float)((idx >> 4) & 15) * 0.0625f - 0.46875f;
    o2 += (float)(idx & 15) * 0.0625f - 0.46875f;

    float* p = out0 + ((size_t)b * 3) * N_ + n;
    p[0]              = o0;
    p[N_]             = o1;
    p[2 * (size_t)N_] = o2;
    reg_out[(size_t)b * N_ + n] = reg;
}

// ---------------------------------------------------------------------------
extern "C" void kernel_launch(void* const* d_in, const int* in_sizes, int n_in,
                              void* d_out, int out_size, void* d_ws, size_t ws_size,
                              hipStream_t stream) {
    const float* x      = (const float*)d_in[0];  // (B, C, RES, RES, RES)
    const int*   counts = (const int*)  d_in[1];  // (B, G)
    const float* b_rnd  = (const float*)d_in[2];  // (B, 2, N)
    // d_in[3] = grid_o: unused (recomputed exactly from idx bits)
    const float* W1     = (const float*)d_in[4];  // (H, C+2)
    const float* b1     = (const float*)d_in[5];  // (H,)
    const float* W2     = (const float*)d_in[6];  // (3, H)
    const float* b2     = (const float*)d_in[7];  // (3,)

    float* out  = (float*)d_out;                  // (B, 3, N) then (B, N)
    float* rout = out + (size_t)B_ * 3 * N_;

    int* idxarr = (int*)d_ws;                     // B*N ints = 2 MB
    unsigned short* hxb =
        (unsigned short*)((char*)d_ws + (size_t)B_ * N_ * sizeof(int));
                                                  // B*G*H bf16 = 16.8 MB

    dim3 gridA(G_ / TCELL + 1, B_);               // (33, 32): +1 col = scan
    hx_scan_kernel<<<gridA, 256, 0, stream>>>(x, W1, b1, counts, hxb, idxarr);

    dim3 gridB(N_ / 256, B_);
    point_kernel<<<gridB, 256, 0, stream>>>(hxb, b_rnd, W1, W2, b2,
                                            idxarr, out, rout);
}